// Round 4
// baseline (154.613 us; speedup 1.0000x reference)
//
#include <hip/hip_runtime.h>

// Sizes fixed by the reference problem.
#define B_   4
#define NQ_  128
#define NK_  1024
#define DD_  256   // DQ == DK
#define H_   256
#define DV_  256

__device__ __forceinline__ float wave_sum(float v) {
  #pragma unroll
  for (int o = 32; o; o >>= 1) v += __shfl_xor(v, o);
  return v;
}
__device__ __forceinline__ float wave_max(float v) {
  #pragma unroll
  for (int o = 32; o; o >>= 1) v = fmaxf(v, __shfl_xor(v, o));
  return v;
}

// C = A(R x 256) * W(256 x 256).  64x64 tile, 256 threads, 4x4 micro-tile.
// TRANS=false: C[row][h] row-major (qp).  TRANS=true: C[(b*H+h)*NK + k] (kpT).
template <bool TRANS>
__global__ __launch_bounds__(256) void proj_kernel(const float* __restrict__ A,
                                                   const float* __restrict__ W,
                                                   float* __restrict__ C) {
  // stride 68: 16B-aligned rows (68*4=272, 272%16==0), bank shift of 4 per k.
  __shared__ float As[16 * 68];  // [k][row]
  __shared__ float Ws[16 * 68];  // [k][col]
  const int tid  = threadIdx.x;
  const int row0 = blockIdx.x * 64;
  const int col0 = blockIdx.y * 64;
  const int ld_d = tid & 15, ld_r = tid >> 4;   // A-tile loader: 16 d x 16 rows
  const int lw_n = tid & 63, lw_k = tid >> 6;   // W-tile loader: 64 n x 4 k
  const int tn = tid & 15, tm = tid >> 4;       // compute: 16x16 threads
  float acc[4][4] = {};
  for (int kt = 0; kt < DD_ / 16; ++kt) {
    const int k0 = kt * 16;
    #pragma unroll
    for (int p = 0; p < 4; ++p) {
      const int r = p * 16 + ld_r;
      As[ld_d * 68 + r] = A[(size_t)(row0 + r) * DD_ + (k0 + ld_d)];
    }
    #pragma unroll
    for (int p = 0; p < 4; ++p) {
      const int kk = p * 4 + lw_k;
      Ws[kk * 68 + lw_n] = W[(size_t)(k0 + kk) * H_ + (col0 + lw_n)];
    }
    __syncthreads();
    #pragma unroll
    for (int kk = 0; kk < 16; ++kk) {
      const float4 a = *(const float4*)&As[kk * 68 + tm * 4];
      const float4 w = *(const float4*)&Ws[kk * 68 + tn * 4];
      acc[0][0] = fmaf(a.x, w.x, acc[0][0]);
      acc[0][1] = fmaf(a.x, w.y, acc[0][1]);
      acc[0][2] = fmaf(a.x, w.z, acc[0][2]);
      acc[0][3] = fmaf(a.x, w.w, acc[0][3]);
      acc[1][0] = fmaf(a.y, w.x, acc[1][0]);
      acc[1][1] = fmaf(a.y, w.y, acc[1][1]);
      acc[1][2] = fmaf(a.y, w.z, acc[1][2]);
      acc[1][3] = fmaf(a.y, w.w, acc[1][3]);
      acc[2][0] = fmaf(a.z, w.x, acc[2][0]);
      acc[2][1] = fmaf(a.z, w.y, acc[2][1]);
      acc[2][2] = fmaf(a.z, w.z, acc[2][2]);
      acc[2][3] = fmaf(a.z, w.w, acc[2][3]);
      acc[3][0] = fmaf(a.w, w.x, acc[3][0]);
      acc[3][1] = fmaf(a.w, w.y, acc[3][1]);
      acc[3][2] = fmaf(a.w, w.z, acc[3][2]);
      acc[3][3] = fmaf(a.w, w.w, acc[3][3]);
    }
    __syncthreads();
  }
  if (!TRANS) {
    #pragma unroll
    for (int i = 0; i < 4; ++i) {
      float4 v = make_float4(acc[i][0], acc[i][1], acc[i][2], acc[i][3]);
      *(float4*)&C[(size_t)(row0 + tm * 4 + i) * H_ + (col0 + tn * 4)] = v;
    }
  } else {
    #pragma unroll
    for (int i = 0; i < 4; ++i) {
      const int row = row0 + tm * 4 + i;
      const int b = row >> 10;          // NK_=1024 rows per batch
      const int k = row & (NK_ - 1);
      #pragma unroll
      for (int j = 0; j < 4; ++j) {
        const int h = col0 + tn * 4 + j;
        C[((size_t)(b * H_ + h)) * NK_ + k] = acc[i][j];
      }
    }
  }
}

// scores[b,q,k] = sum_h v_w[h] * tanh(qp[b,q,h] + kpT[b,h,k])
//              = Wsum - sum_h (2*v_w[h]) * rcp(1 + exp2((qp+kp)*2*log2e))
// One block per (b,q); thread t owns k = 4t..4t+3 via float4 loads.
__global__ __launch_bounds__(256) void scores_kernel(const float* __restrict__ qp,
                                                     const float* __restrict__ kpT,
                                                     const float* __restrict__ v_w,
                                                     float* __restrict__ scores) {
  __shared__ float qs[H_];
  __shared__ float w2s[H_];
  __shared__ float reds[4];
  const int tid = threadIdx.x;
  const int row = blockIdx.x;      // b*NQ + q
  const int b = row >> 7;          // NQ_=128
  qs[tid] = qp[(size_t)row * H_ + tid];
  const float vw = v_w[tid];
  w2s[tid] = 2.0f * vw;
  float s = wave_sum(vw);
  if ((tid & 63) == 0) reds[tid >> 6] = s;
  __syncthreads();
  const float wsum = reds[0] + reds[1] + reds[2] + reds[3];

  const float C2 = 2.8853900817779268f;  // 2*log2(e)
  float acc0 = 0.f, acc1 = 0.f, acc2 = 0.f, acc3 = 0.f;
  const float* kp = kpT + (size_t)b * H_ * NK_ + (size_t)tid * 4;
  #pragma unroll 4
  for (int h = 0; h < H_; ++h) {
    const float4 kv = *(const float4*)(kp + (size_t)h * NK_);
    const float q = qs[h];
    const float w2 = w2s[h];
    const float e0 = __builtin_amdgcn_exp2f((q + kv.x) * C2);
    const float e1 = __builtin_amdgcn_exp2f((q + kv.y) * C2);
    const float e2 = __builtin_amdgcn_exp2f((q + kv.z) * C2);
    const float e3 = __builtin_amdgcn_exp2f((q + kv.w) * C2);
    acc0 = fmaf(w2, __builtin_amdgcn_rcpf(1.0f + e0), acc0);
    acc1 = fmaf(w2, __builtin_amdgcn_rcpf(1.0f + e1), acc1);
    acc2 = fmaf(w2, __builtin_amdgcn_rcpf(1.0f + e2), acc2);
    acc3 = fmaf(w2, __builtin_amdgcn_rcpf(1.0f + e3), acc3);
  }
  float4 o;
  o.x = wsum - acc0;
  o.y = wsum - acc1;
  o.z = wsum - acc2;
  o.w = wsum - acc3;
  *(float4*)(scores + (size_t)row * NK_ + (size_t)tid * 4) = o;
}

// Masked softmax over k, then out[b,q,d] = sum_k w[k] * values[b,k,d].
// One block per (b,q); 256 threads; thread d owns output dim d.
__global__ __launch_bounds__(256) void softmax_pv_kernel(const float* __restrict__ scores,
                                                         const float* __restrict__ values,
                                                         const int* __restrict__ valid_lens,
                                                         float* __restrict__ out) {
  __shared__ float wlds[NK_];
  __shared__ float redm[4];
  __shared__ float redsum[4];
  const int tid = threadIdx.x;
  const int row = blockIdx.x;   // b*NQ + q
  const int b = row >> 7;
  int vl = valid_lens[b];
  vl = vl < 1 ? 1 : (vl > NK_ ? NK_ : vl);
  const int k0 = tid * 4;
  const float4 sc = *(const float4*)(scores + (size_t)row * NK_ + k0);
  const float NEG = -3.0e38f;
  float m = NEG;
  m = fmaxf(m, (k0 + 0 < vl) ? sc.x : NEG);
  m = fmaxf(m, (k0 + 1 < vl) ? sc.y : NEG);
  m = fmaxf(m, (k0 + 2 < vl) ? sc.z : NEG);
  m = fmaxf(m, (k0 + 3 < vl) ? sc.w : NEG);
  m = wave_max(m);
  if ((tid & 63) == 0) redm[tid >> 6] = m;
  __syncthreads();
  const float M = fmaxf(fmaxf(redm[0], redm[1]), fmaxf(redm[2], redm[3]));
  const float CE = 1.4426950408889634f;  // log2(e)
  const float p0 = (k0 + 0 < vl) ? __builtin_amdgcn_exp2f((sc.x - M) * CE) : 0.0f;
  const float p1 = (k0 + 1 < vl) ? __builtin_amdgcn_exp2f((sc.y - M) * CE) : 0.0f;
  const float p2 = (k0 + 2 < vl) ? __builtin_amdgcn_exp2f((sc.z - M) * CE) : 0.0f;
  const float p3 = (k0 + 3 < vl) ? __builtin_amdgcn_exp2f((sc.w - M) * CE) : 0.0f;
  float psum = wave_sum(p0 + p1 + p2 + p3);
  if ((tid & 63) == 0) redsum[tid >> 6] = psum;
  __syncthreads();
  const float S = redsum[0] + redsum[1] + redsum[2] + redsum[3];
  const float inv = 1.0f / S;
  wlds[k0 + 0] = p0 * inv;
  wlds[k0 + 1] = p1 * inv;
  wlds[k0 + 2] = p2 * inv;
  wlds[k0 + 3] = p3 * inv;
  __syncthreads();

  const float* vb = values + (size_t)b * NK_ * DV_ + tid;
  float a0 = 0.f, a1 = 0.f, a2 = 0.f, a3 = 0.f;
  int k = 0;
  const int vl4 = vl & ~3;
  for (; k < vl4; k += 4) {
    a0 = fmaf(wlds[k + 0], vb[(size_t)(k + 0) * DV_], a0);
    a1 = fmaf(wlds[k + 1], vb[(size_t)(k + 1) * DV_], a1);
    a2 = fmaf(wlds[k + 2], vb[(size_t)(k + 2) * DV_], a2);
    a3 = fmaf(wlds[k + 3], vb[(size_t)(k + 3) * DV_], a3);
  }
  for (; k < vl; ++k) a0 = fmaf(wlds[k], vb[(size_t)k * DV_], a0);
  out[(size_t)row * DV_ + tid] = (a0 + a1) + (a2 + a3);
}

extern "C" void kernel_launch(void* const* d_in, const int* in_sizes, int n_in,
                              void* d_out, int out_size, void* d_ws, size_t ws_size,
                              hipStream_t stream) {
  const float* queries = (const float*)d_in[0];  // (B, NQ, DQ)
  const float* keys    = (const float*)d_in[1];  // (B, NK, DK)
  const float* values  = (const float*)d_in[2];  // (B, NK, DV)
  const int*   vlens   = (const int*)d_in[3];    // (B,)
  const float* W_q     = (const float*)d_in[4];  // (DQ, H)
  const float* W_k     = (const float*)d_in[5];  // (DK, H)
  const float* v_w     = (const float*)d_in[6];  // (H,)
  float* out = (float*)d_out;                    // (B, NQ, DV)

  // Workspace layout (floats): qp | kpT | scores  = 0.5MB + 4MB + 2MB = 6.5MB
  float* qp     = (float*)d_ws;                  // [B*NQ][H]
  float* kpT    = qp + (size_t)B_ * NQ_ * H_;    // [B][H][NK]
  float* scores = kpT + (size_t)B_ * H_ * NK_;   // [B*NQ][NK]

  proj_kernel<false><<<dim3((B_ * NQ_) / 64, H_ / 64), 256, 0, stream>>>(queries, W_q, qp);
  proj_kernel<true ><<<dim3((B_ * NK_) / 64, H_ / 64), 256, 0, stream>>>(keys, W_k, kpT);
  scores_kernel<<<B_ * NQ_, 256, 0, stream>>>(qp, kpT, v_w, scores);
  softmax_pv_kernel<<<B_ * NQ_, 256, 0, stream>>>(scores, values, vlens, out);
}

// Round 5
// 150.111 us; speedup vs baseline: 1.0300x; 1.0300x over previous
//
#include <hip/hip_runtime.h>

// Sizes fixed by the reference problem.
#define B_   4
#define NQ_  128
#define NK_  1024
#define DD_  256   // DQ == DK
#define H_   256
#define DV_  256
#define QB   2     // q rows per fused block

__device__ __forceinline__ float wave_sum(float v) {
  #pragma unroll
  for (int o = 32; o; o >>= 1) v += __shfl_xor(v, o);
  return v;
}
__device__ __forceinline__ float wave_max(float v) {
  #pragma unroll
  for (int o = 32; o; o >>= 1) v = fmaxf(v, __shfl_xor(v, o));
  return v;
}

// C = A(R x 256) * W(256 x 256).  64x64 tile, 256 threads, 4x4 micro-tile.
// TRANS=false: C[row][h] row-major (qp).  TRANS=true: C[(b*H+h)*NK + k] (kpT).
template <bool TRANS>
__global__ __launch_bounds__(256) void proj_kernel(const float* __restrict__ A,
                                                   const float* __restrict__ W,
                                                   float* __restrict__ C) {
  __shared__ float As[16 * 68];  // [k][row]
  __shared__ float Ws[16 * 68];  // [k][col]
  const int tid  = threadIdx.x;
  const int row0 = blockIdx.x * 64;
  const int col0 = blockIdx.y * 64;
  const int ld_d = tid & 15, ld_r = tid >> 4;   // A-tile loader: 16 d x 16 rows
  const int lw_n = tid & 63, lw_k = tid >> 6;   // W-tile loader: 64 n x 4 k
  const int tn = tid & 15, tm = tid >> 4;       // compute: 16x16 threads
  float acc[4][4] = {};
  for (int kt = 0; kt < DD_ / 16; ++kt) {
    const int k0 = kt * 16;
    #pragma unroll
    for (int p = 0; p < 4; ++p) {
      const int r = p * 16 + ld_r;
      As[ld_d * 68 + r] = A[(size_t)(row0 + r) * DD_ + (k0 + ld_d)];
    }
    #pragma unroll
    for (int p = 0; p < 4; ++p) {
      const int kk = p * 4 + lw_k;
      Ws[kk * 68 + lw_n] = W[(size_t)(k0 + kk) * H_ + (col0 + lw_n)];
    }
    __syncthreads();
    #pragma unroll
    for (int kk = 0; kk < 16; ++kk) {
      const float4 a = *(const float4*)&As[kk * 68 + tm * 4];
      const float4 w = *(const float4*)&Ws[kk * 68 + tn * 4];
      acc[0][0] = fmaf(a.x, w.x, acc[0][0]);
      acc[0][1] = fmaf(a.x, w.y, acc[0][1]);
      acc[0][2] = fmaf(a.x, w.z, acc[0][2]);
      acc[0][3] = fmaf(a.x, w.w, acc[0][3]);
      acc[1][0] = fmaf(a.y, w.x, acc[1][0]);
      acc[1][1] = fmaf(a.y, w.y, acc[1][1]);
      acc[1][2] = fmaf(a.y, w.z, acc[1][2]);
      acc[1][3] = fmaf(a.y, w.w, acc[1][3]);
      acc[2][0] = fmaf(a.z, w.x, acc[2][0]);
      acc[2][1] = fmaf(a.z, w.y, acc[2][1]);
      acc[2][2] = fmaf(a.z, w.z, acc[2][2]);
      acc[2][3] = fmaf(a.z, w.w, acc[2][3]);
      acc[3][0] = fmaf(a.w, w.x, acc[3][0]);
      acc[3][1] = fmaf(a.w, w.y, acc[3][1]);
      acc[3][2] = fmaf(a.w, w.z, acc[3][2]);
      acc[3][3] = fmaf(a.w, w.w, acc[3][3]);
    }
    __syncthreads();
  }
  if (!TRANS) {
    #pragma unroll
    for (int i = 0; i < 4; ++i) {
      float4 v = make_float4(acc[i][0], acc[i][1], acc[i][2], acc[i][3]);
      *(float4*)&C[(size_t)(row0 + tm * 4 + i) * H_ + (col0 + tn * 4)] = v;
    }
  } else {
    #pragma unroll
    for (int i = 0; i < 4; ++i) {
      const int row = row0 + tm * 4 + i;
      const int b = row >> 10;          // NK_=1024 rows per batch
      const int k = row & (NK_ - 1);
      #pragma unroll
      for (int j = 0; j < 4; ++j) {
        const int h = col0 + tn * 4 + j;
        C[((size_t)(b * H_ + h)) * NK_ + k] = acc[i][j];
      }
    }
  }
}

// Fused scores + masked softmax + PV.
// One block per QB=2 q rows of one batch; 512 threads (8 waves).
// Phase 1 (scores): thread t owns k = 2t..2t+1 for BOTH q rows (shares kpT load).
//   score = wsum - sum_h (2 v_h) * rcp(1 + exp2((q_h + k_h)*2*log2e))  [tanh identity]
//   Threads with k >= valid_len skip the h-loop (ref masks them to -1e6 anyway).
// Phase 2 (softmax): thread t -> (qi = t>>8, float4 group j = t&255); in-place
//   weights written back into s_lds.
// Phase 3 (PV): wave w owns k in [128w, 128w+128) ∩ [0, vl); lane owns d = 4*lane
//   via float4 V loads; per-wave partials reduced through LDS.
__global__ __launch_bounds__(512) void fused_attn_kernel(const float* __restrict__ qp,
                                                         const float* __restrict__ kpT,
                                                         const float* __restrict__ v_w,
                                                         const float* __restrict__ values,
                                                         const int* __restrict__ valid_lens,
                                                         float* __restrict__ out) {
  __shared__ float qs[QB][H_];
  __shared__ float w2s[H_];
  __shared__ float reds[4];
  __shared__ float s_lds[QB][NK_];
  __shared__ float redm[QB][4];
  __shared__ float redsum[QB][4];
  __shared__ float red[8][QB][DV_];

  const int tid = threadIdx.x;  // 0..511
  // Batch<->XCD affinity swizzle: consecutive blocks round-robin XCDs (n&7);
  // give XCDs {2b,2b+1} only batch b so its 2MB (kpT+V) fits the 4MB L2.
  const int n = blockIdx.x;     // 0..255
  const int xcd = n & 7;
  const int b = xcd >> 1;
  const int idx = ((n >> 3) << 1) | (xcd & 1);  // 0..63 q-pair within batch

  int vl = valid_lens[b];
  vl = vl < 1 ? 1 : (vl > NK_ ? NK_ : vl);

  // Stage q rows, 2*v_w, and wsum = sum_h v_w[h].
  if (tid < H_) {
    const float vw = v_w[tid];
    w2s[tid] = 2.0f * vw;
    float s = wave_sum(vw);
    if ((tid & 63) == 0) reds[tid >> 6] = s;
  }
  {
    const int qi = tid >> 8, h = tid & 255;
    qs[qi][h] = qp[(size_t)(b * NQ_ + idx * QB + qi) * H_ + h];
  }
  __syncthreads();
  const float wsum = reds[0] + reds[1] + reds[2] + reds[3];

  // ---- Phase 1: scores ----
  const int k0 = tid * 2;
  const float C2 = 2.8853900817779268f;  // 2*log2(e)
  if (k0 < vl) {
    float a00 = 0.f, a01 = 0.f, a10 = 0.f, a11 = 0.f;
    const float* kp = kpT + (size_t)b * H_ * NK_ + k0;
    #pragma unroll 4
    for (int h = 0; h < H_; ++h) {
      const float2 kv = *(const float2*)(kp + (size_t)h * NK_);
      const float w2 = w2s[h];
      const float q0 = qs[0][h];
      const float q1 = qs[1][h];
      const float e00 = __builtin_amdgcn_exp2f((q0 + kv.x) * C2);
      const float e01 = __builtin_amdgcn_exp2f((q0 + kv.y) * C2);
      const float e10 = __builtin_amdgcn_exp2f((q1 + kv.x) * C2);
      const float e11 = __builtin_amdgcn_exp2f((q1 + kv.y) * C2);
      a00 = fmaf(w2, __builtin_amdgcn_rcpf(1.0f + e00), a00);
      a01 = fmaf(w2, __builtin_amdgcn_rcpf(1.0f + e01), a01);
      a10 = fmaf(w2, __builtin_amdgcn_rcpf(1.0f + e10), a10);
      a11 = fmaf(w2, __builtin_amdgcn_rcpf(1.0f + e11), a11);
    }
    *(float2*)&s_lds[0][k0] = make_float2(wsum - a00, wsum - a01);
    *(float2*)&s_lds[1][k0] = make_float2(wsum - a10, wsum - a11);
  }
  __syncthreads();

  // ---- Phase 2: masked softmax over k (rows done in parallel) ----
  const int qi = tid >> 8;
  const int kk0 = (tid & 255) * 4;
  const float4 s4 = *(const float4*)&s_lds[qi][kk0];
  const float NEG = -3.0e38f;
  float m = NEG;
  m = fmaxf(m, (kk0 + 0 < vl) ? s4.x : NEG);
  m = fmaxf(m, (kk0 + 1 < vl) ? s4.y : NEG);
  m = fmaxf(m, (kk0 + 2 < vl) ? s4.z : NEG);
  m = fmaxf(m, (kk0 + 3 < vl) ? s4.w : NEG);
  m = wave_max(m);
  if ((tid & 63) == 0) redm[qi][(tid >> 6) & 3] = m;
  __syncthreads();
  const float M = fmaxf(fmaxf(redm[qi][0], redm[qi][1]), fmaxf(redm[qi][2], redm[qi][3]));
  const float CE = 1.4426950408889634f;  // log2(e)
  const float p0 = (kk0 + 0 < vl) ? __builtin_amdgcn_exp2f((s4.x - M) * CE) : 0.0f;
  const float p1 = (kk0 + 1 < vl) ? __builtin_amdgcn_exp2f((s4.y - M) * CE) : 0.0f;
  const float p2 = (kk0 + 2 < vl) ? __builtin_amdgcn_exp2f((s4.z - M) * CE) : 0.0f;
  const float p3 = (kk0 + 3 < vl) ? __builtin_amdgcn_exp2f((s4.w - M) * CE) : 0.0f;
  float psum = wave_sum(p0 + p1 + p2 + p3);
  if ((tid & 63) == 0) redsum[qi][(tid >> 6) & 3] = psum;
  __syncthreads();
  const float S = redsum[qi][0] + redsum[qi][1] + redsum[qi][2] + redsum[qi][3];
  const float inv = 1.0f / S;
  *(float4*)&s_lds[qi][kk0] = make_float4(p0 * inv, p1 * inv, p2 * inv, p3 * inv);
  __syncthreads();

  // ---- Phase 3: PV ----
  const int w = tid >> 6;
  const int lane = tid & 63;
  const int d0 = lane * 4;
  float4 pa0 = make_float4(0.f, 0.f, 0.f, 0.f);
  float4 pa1 = make_float4(0.f, 0.f, 0.f, 0.f);
  const int kbeg = w * (NK_ / 8);
  const int kend = (kbeg + NK_ / 8) < vl ? (kbeg + NK_ / 8) : vl;
  const float* vb = values + (size_t)b * NK_ * DV_ + d0;
  #pragma unroll 4
  for (int k = kbeg; k < kend; ++k) {
    const float4 v4 = *(const float4*)(vb + (size_t)k * DV_);
    const float w0 = s_lds[0][k];
    const float w1 = s_lds[1][k];
    pa0.x = fmaf(w0, v4.x, pa0.x);
    pa0.y = fmaf(w0, v4.y, pa0.y);
    pa0.z = fmaf(w0, v4.z, pa0.z);
    pa0.w = fmaf(w0, v4.w, pa0.w);
    pa1.x = fmaf(w1, v4.x, pa1.x);
    pa1.y = fmaf(w1, v4.y, pa1.y);
    pa1.z = fmaf(w1, v4.z, pa1.z);
    pa1.w = fmaf(w1, v4.w, pa1.w);
  }
  *(float4*)&red[w][0][d0] = pa0;
  *(float4*)&red[w][1][d0] = pa1;
  __syncthreads();

  // Combine 8 wave-partials; coalesced store.
  const int oqi = tid >> 8;
  const int d = tid & 255;
  float s = 0.f;
  #pragma unroll
  for (int ww = 0; ww < 8; ++ww) s += red[ww][oqi][d];
  out[(size_t)(b * NQ_ + idx * QB + oqi) * DV_ + d] = s;
}

extern "C" void kernel_launch(void* const* d_in, const int* in_sizes, int n_in,
                              void* d_out, int out_size, void* d_ws, size_t ws_size,
                              hipStream_t stream) {
  const float* queries = (const float*)d_in[0];  // (B, NQ, DQ)
  const float* keys    = (const float*)d_in[1];  // (B, NK, DK)
  const float* values  = (const float*)d_in[2];  // (B, NK, DV)
  const int*   vlens   = (const int*)d_in[3];    // (B,)
  const float* W_q     = (const float*)d_in[4];  // (DQ, H)
  const float* W_k     = (const float*)d_in[5];  // (DK, H)
  const float* v_w     = (const float*)d_in[6];  // (H,)
  float* out = (float*)d_out;                    // (B, NQ, DV)

  // Workspace layout (floats): qp | kpT  = 0.5MB + 4MB
  float* qp  = (float*)d_ws;                  // [B*NQ][H]
  float* kpT = qp + (size_t)B_ * NQ_ * H_;    // [B][H][NK]

  proj_kernel<false><<<dim3((B_ * NQ_) / 64, H_ / 64), 256, 0, stream>>>(queries, W_q, qp);
  proj_kernel<true ><<<dim3((B_ * NK_) / 64, H_ / 64), 256, 0, stream>>>(keys, W_k, kpT);
  fused_attn_kernel<<<(B_ * NQ_) / QB, 512, 0, stream>>>(qp, kpT, v_w, values, vlens, out);
}

// Round 10
// 132.096 us; speedup vs baseline: 1.1705x; 1.1364x over previous
//
#include <hip/hip_runtime.h>

// Sizes fixed by the reference problem.
#define B_   4
#define NQ_  128
#define NK_  1024
#define DD_  256   // DQ == DK
#define H_   256
#define DV_  256

__device__ __forceinline__ float wave_sum(float v) {
  #pragma unroll
  for (int o = 32; o; o >>= 1) v += __shfl_xor(v, o);
  return v;
}
__device__ __forceinline__ float wave_max(float v) {
  #pragma unroll
  for (int o = 32; o; o >>= 1) v = fmaxf(v, __shfl_xor(v, o));
  return v;
}

// Merged projection GEMM over 4608 rows:
//   rows [0,512):    qp[row][h]        = queries * W_q   (row-major store)
//   rows [512,4608): kpT[b][h][k]      = keys * W_k      (transposed store via LDS)
// 64x64 tile, 256 threads, 4x4 micro-tile, register-prefetch double buffering.
__global__ __launch_bounds__(256) void proj_merged_kernel(
    const float* __restrict__ queries, const float* __restrict__ keys,
    const float* __restrict__ W_q, const float* __restrict__ W_k,
    float* __restrict__ qp, float* __restrict__ kpT) {
  __shared__ float As[16 * 68];   // [k16][row64] (+pad)
  __shared__ float Ws[16 * 68];   // [k16][col64] (+pad)
  __shared__ float Ts[64 * 68];   // transpose staging [h][k] (+pad, 16B-aligned rows)
  const int tid  = threadIdx.x;
  const int row0 = blockIdx.x * 64;
  const int col0 = blockIdx.y * 64;
  const bool isQ = row0 < 512;
  const float* A = isQ ? queries + (size_t)row0 * DD_
                       : keys + (size_t)(row0 - 512) * DD_;
  const float* W = isQ ? W_q : W_k;
  const int ld_d = tid & 15, ld_r = tid >> 4;   // A loader: 16 d x 16 r (x4 passes)
  const int lw_n = tid & 63, lw_k = tid >> 6;   // W loader: 64 n x 4 k (x4 passes)
  const int tn = tid & 15, tm = tid >> 4;       // compute: 16x16 threads

  float aP[4], wP[4];
  #pragma unroll
  for (int p = 0; p < 4; ++p) aP[p] = A[(size_t)(p * 16 + ld_r) * DD_ + ld_d];
  #pragma unroll
  for (int p = 0; p < 4; ++p) wP[p] = W[(size_t)(p * 4 + lw_k) * H_ + col0 + lw_n];

  float acc[4][4] = {};
  for (int kt = 0; kt < 16; ++kt) {
    __syncthreads();   // previous compute done reading LDS
    #pragma unroll
    for (int p = 0; p < 4; ++p) As[ld_d * 68 + p * 16 + ld_r] = aP[p];
    #pragma unroll
    for (int p = 0; p < 4; ++p) Ws[(p * 4 + lw_k) * 68 + lw_n] = wP[p];
    __syncthreads();
    if (kt < 15) {     // prefetch next tile while computing this one
      const int k0 = (kt + 1) * 16;
      #pragma unroll
      for (int p = 0; p < 4; ++p) aP[p] = A[(size_t)(p * 16 + ld_r) * DD_ + k0 + ld_d];
      #pragma unroll
      for (int p = 0; p < 4; ++p) wP[p] = W[(size_t)(k0 + p * 4 + lw_k) * H_ + col0 + lw_n];
    }
    #pragma unroll
    for (int kk = 0; kk < 16; ++kk) {
      const float4 a = *(const float4*)&As[kk * 68 + tm * 4];
      const float4 w = *(const float4*)&Ws[kk * 68 + tn * 4];
      acc[0][0] = fmaf(a.x, w.x, acc[0][0]);
      acc[0][1] = fmaf(a.x, w.y, acc[0][1]);
      acc[0][2] = fmaf(a.x, w.z, acc[0][2]);
      acc[0][3] = fmaf(a.x, w.w, acc[0][3]);
      acc[1][0] = fmaf(a.y, w.x, acc[1][0]);
      acc[1][1] = fmaf(a.y, w.y, acc[1][1]);
      acc[1][2] = fmaf(a.y, w.z, acc[1][2]);
      acc[1][3] = fmaf(a.y, w.w, acc[1][3]);
      acc[2][0] = fmaf(a.z, w.x, acc[2][0]);
      acc[2][1] = fmaf(a.z, w.y, acc[2][1]);
      acc[2][2] = fmaf(a.z, w.z, acc[2][2]);
      acc[2][3] = fmaf(a.z, w.w, acc[2][3]);
      acc[3][0] = fmaf(a.w, w.x, acc[3][0]);
      acc[3][1] = fmaf(a.w, w.y, acc[3][1]);
      acc[3][2] = fmaf(a.w, w.z, acc[3][2]);
      acc[3][3] = fmaf(a.w, w.w, acc[3][3]);
    }
  }

  if (isQ) {
    #pragma unroll
    for (int i = 0; i < 4; ++i) {
      *(float4*)&qp[(size_t)(row0 + tm * 4 + i) * H_ + col0 + tn * 4] =
          make_float4(acc[i][0], acc[i][1], acc[i][2], acc[i][3]);
    }
  } else {
    // Transpose 64(row=k) x 64(col=h) tile in LDS, then coalesced store.
    #pragma unroll
    for (int i = 0; i < 4; ++i)
      #pragma unroll
      for (int j = 0; j < 4; ++j)
        Ts[(tn * 4 + j) * 68 + tm * 4 + i] = acc[i][j];
    __syncthreads();
    const int keyrow = row0 - 512;
    const int b = keyrow >> 10;            // NK_=1024 rows per batch
    const int kbase = keyrow & (NK_ - 1);
    const int hh = tid >> 2;               // 64 h rows
    const int kg = (tid & 3) * 16;         // 16-k group within the 64-k tile
    float* dst = kpT + ((size_t)(b * H_ + col0 + hh)) * NK_ + kbase + kg;
    #pragma unroll
    for (int p = 0; p < 4; ++p)
      *(float4*)&dst[p * 4] = *(const float4*)&Ts[hh * 68 + kg + p * 4];
  }
}

// Fused scores + masked softmax + PV.
// One block per 2 q rows of one batch; 512 threads (8 waves).
// Phase 1: group g = tid>>8 covers h in [128g, 128g+128); thread owns k = 4t..4t+3
//   (float4 kv) for BOTH q rows -> 8 independent exp2/rcp chains.
//   score = wsum - sum_h (2 v_h) * rcp(1 + exp2((q_h + k_h)*2*log2e))  [tanh identity]
//   Threads with k >= valid_len skip the h-loop entirely.
// Phase 2: combine the two h-halves, masked softmax per q row.
// Phase 3: wave w owns k in [128w, 128w+128) ∩ [0, vl); lane owns d = 4*lane.
__global__ __launch_bounds__(512) void fused_attn_kernel(
    const float* __restrict__ qp, const float* __restrict__ kpT,
    const float* __restrict__ v_w, const float* __restrict__ values,
    const int* __restrict__ valid_lens, float* __restrict__ out) {
  __shared__ float2 qs2[H_];            // {q0*C2, q1*C2}
  __shared__ float w2s[H_];
  __shared__ float reds[4];
  __shared__ float s_half[2][2][NK_];   // [h-half][qi][k] partial sums -> weights
  __shared__ float redm[2][4];
  __shared__ float redsum[2][4];
  __shared__ float red[8][2][DV_];

  const int tid = threadIdx.x;  // 0..511
  // Batch<->XCD affinity: XCD pair {2b,2b+1} only touches batch b (2MB fits L2).
  const int n = blockIdx.x;     // 0..255
  const int xcd = n & 7;
  const int b = xcd >> 1;
  const int idx = ((n >> 3) << 1) | (xcd & 1);  // 0..63 q-pair within batch
  const int qrow = b * NQ_ + idx * 2;

  int vl = valid_lens[b];
  vl = vl < 1 ? 1 : (vl > NK_ ? NK_ : vl);

  const float C2 = 2.8853900817779268f;  // 2*log2(e)
  if (tid < H_) {
    const float vw = v_w[tid];
    w2s[tid] = 2.0f * vw;
    const float q0 = qp[(size_t)qrow * H_ + tid];
    const float q1 = qp[(size_t)(qrow + 1) * H_ + tid];
    qs2[tid] = make_float2(q0 * C2, q1 * C2);
    float s = wave_sum(vw);
    if ((tid & 63) == 0) reds[tid >> 6] = s;
  }
  __syncthreads();
  const float wsum = reds[0] + reds[1] + reds[2] + reds[3];

  // ---- Phase 1: partial score sums over this group's h-half ----
  const int g = tid >> 8;
  const int t = tid & 255;
  const int k0 = t * 4;
  if (k0 < vl) {
    float a0x = 0.f, a0y = 0.f, a0z = 0.f, a0w = 0.f;
    float a1x = 0.f, a1y = 0.f, a1z = 0.f, a1w = 0.f;
    const float* kp = kpT + (size_t)b * H_ * NK_ + (size_t)(g * 128) * NK_ + k0;
    #pragma unroll 2
    for (int h = 0; h < 128; ++h) {
      const float4 kv = *(const float4*)(kp + (size_t)h * NK_);
      const int hh = g * 128 + h;
      const float w2 = w2s[hh];
      const float2 q2 = qs2[hh];
      const float e0x = __builtin_amdgcn_exp2f(fmaf(kv.x, C2, q2.x));
      const float e0y = __builtin_amdgcn_exp2f(fmaf(kv.y, C2, q2.x));
      const float e0z = __builtin_amdgcn_exp2f(fmaf(kv.z, C2, q2.x));
      const float e0w = __builtin_amdgcn_exp2f(fmaf(kv.w, C2, q2.x));
      const float e1x = __builtin_amdgcn_exp2f(fmaf(kv.x, C2, q2.y));
      const float e1y = __builtin_amdgcn_exp2f(fmaf(kv.y, C2, q2.y));
      const float e1z = __builtin_amdgcn_exp2f(fmaf(kv.z, C2, q2.y));
      const float e1w = __builtin_amdgcn_exp2f(fmaf(kv.w, C2, q2.y));
      a0x = fmaf(w2, __builtin_amdgcn_rcpf(1.0f + e0x), a0x);
      a0y = fmaf(w2, __builtin_amdgcn_rcpf(1.0f + e0y), a0y);
      a0z = fmaf(w2, __builtin_amdgcn_rcpf(1.0f + e0z), a0z);
      a0w = fmaf(w2, __builtin_amdgcn_rcpf(1.0f + e0w), a0w);
      a1x = fmaf(w2, __builtin_amdgcn_rcpf(1.0f + e1x), a1x);
      a1y = fmaf(w2, __builtin_amdgcn_rcpf(1.0f + e1y), a1y);
      a1z = fmaf(w2, __builtin_amdgcn_rcpf(1.0f + e1z), a1z);
      a1w = fmaf(w2, __builtin_amdgcn_rcpf(1.0f + e1w), a1w);
    }
    *(float4*)&s_half[g][0][k0] = make_float4(a0x, a0y, a0z, a0w);
    *(float4*)&s_half[g][1][k0] = make_float4(a1x, a1y, a1z, a1w);
  }
  __syncthreads();

  // ---- Phase 2: combine halves + masked softmax per q row ----
  const int qi = tid >> 8;
  const int k4 = (tid & 255) * 4;
  const float4 pA = *(const float4*)&s_half[0][qi][k4];
  const float4 pB = *(const float4*)&s_half[1][qi][k4];
  const float s0 = wsum - (pA.x + pB.x);
  const float s1 = wsum - (pA.y + pB.y);
  const float s2 = wsum - (pA.z + pB.z);
  const float s3 = wsum - (pA.w + pB.w);
  const float NEG = -3.0e38f;
  float m = NEG;
  m = fmaxf(m, (k4 + 0 < vl) ? s0 : NEG);
  m = fmaxf(m, (k4 + 1 < vl) ? s1 : NEG);
  m = fmaxf(m, (k4 + 2 < vl) ? s2 : NEG);
  m = fmaxf(m, (k4 + 3 < vl) ? s3 : NEG);
  m = wave_max(m);
  if ((tid & 63) == 0) redm[qi][(tid >> 6) & 3] = m;
  __syncthreads();
  const float M = fmaxf(fmaxf(redm[qi][0], redm[qi][1]),
                        fmaxf(redm[qi][2], redm[qi][3]));
  const float CE = 1.4426950408889634f;  // log2(e)
  const float p0 = (k4 + 0 < vl) ? __builtin_amdgcn_exp2f((s0 - M) * CE) : 0.0f;
  const float p1 = (k4 + 1 < vl) ? __builtin_amdgcn_exp2f((s1 - M) * CE) : 0.0f;
  const float p2 = (k4 + 2 < vl) ? __builtin_amdgcn_exp2f((s2 - M) * CE) : 0.0f;
  const float p3 = (k4 + 3 < vl) ? __builtin_amdgcn_exp2f((s3 - M) * CE) : 0.0f;
  float psum = wave_sum(p0 + p1 + p2 + p3);
  if ((tid & 63) == 0) redsum[qi][(tid >> 6) & 3] = psum;
  __syncthreads();
  const float S = redsum[qi][0] + redsum[qi][1] + redsum[qi][2] + redsum[qi][3];
  const float inv = 1.0f / S;
  *(float4*)&s_half[0][qi][k4] = make_float4(p0 * inv, p1 * inv, p2 * inv, p3 * inv);
  __syncthreads();

  // ---- Phase 3: PV ----
  const int w = tid >> 6;
  const int lane = tid & 63;
  const int d0 = lane * 4;
  float4 pa0 = make_float4(0.f, 0.f, 0.f, 0.f);
  float4 pa1 = make_float4(0.f, 0.f, 0.f, 0.f);
  const int kbeg = w * (NK_ / 8);
  const int kend = (kbeg + NK_ / 8) < vl ? (kbeg + NK_ / 8) : vl;
  const float* vb = values + (size_t)b * NK_ * DV_ + d0;
  #pragma unroll 4
  for (int k = kbeg; k < kend; ++k) {
    const float4 v4 = *(const float4*)(vb + (size_t)k * DV_);
    const float w0 = s_half[0][0][k];
    const float w1 = s_half[0][1][k];
    pa0.x = fmaf(w0, v4.x, pa0.x);
    pa0.y = fmaf(w0, v4.y, pa0.y);
    pa0.z = fmaf(w0, v4.z, pa0.z);
    pa0.w = fmaf(w0, v4.w, pa0.w);
    pa1.x = fmaf(w1, v4.x, pa1.x);
    pa1.y = fmaf(w1, v4.y, pa1.y);
    pa1.z = fmaf(w1, v4.z, pa1.z);
    pa1.w = fmaf(w1, v4.w, pa1.w);
  }
  *(float4*)&red[w][0][d0] = pa0;
  *(float4*)&red[w][1][d0] = pa1;
  __syncthreads();

  // Combine 8 wave-partials; coalesced store.
  const int oqi = tid >> 8;
  const int d = tid & 255;
  float s = 0.f;
  #pragma unroll
  for (int ww = 0; ww < 8; ++ww) s += red[ww][oqi][d];
  out[(size_t)(qrow + oqi) * DV_ + d] = s;
}

extern "C" void kernel_launch(void* const* d_in, const int* in_sizes, int n_in,
                              void* d_out, int out_size, void* d_ws, size_t ws_size,
                              hipStream_t stream) {
  const float* queries = (const float*)d_in[0];  // (B, NQ, DQ)
  const float* keys    = (const float*)d_in[1];  // (B, NK, DK)
  const float* values  = (const float*)d_in[2];  // (B, NK, DV)
  const int*   vlens   = (const int*)d_in[3];    // (B,)
  const float* W_q     = (const float*)d_in[4];  // (DQ, H)
  const float* W_k     = (const float*)d_in[5];  // (DK, H)
  const float* v_w     = (const float*)d_in[6];  // (H,)
  float* out = (float*)d_out;                    // (B, NQ, DV)

  // Workspace layout (floats): qp | kpT  = 0.5MB + 4MB
  float* qp  = (float*)d_ws;                  // [B*NQ][H]
  float* kpT = qp + (size_t)B_ * NQ_ * H_;    // [B][H][NK]

  proj_merged_kernel<<<dim3((512 + B_ * NK_) / 64, H_ / 64), 256, 0, stream>>>(
      queries, keys, W_q, W_k, qp, kpT);
  fused_attn_kernel<<<(B_ * NQ_) / 2, 512, 0, stream>>>(qp, kpT, v_w, values, vlens, out);
}

// Round 11
// 123.531 us; speedup vs baseline: 1.2516x; 1.0693x over previous
//
#include <hip/hip_runtime.h>

// Sizes fixed by the reference problem.
#define B_   4
#define NQ_  128
#define NK_  1024
#define DD_  256   // DQ == DK
#define H_   256
#define DV_  256

__device__ __forceinline__ float wave_sum(float v) {
  #pragma unroll
  for (int o = 32; o; o >>= 1) v += __shfl_xor(v, o);
  return v;
}
__device__ __forceinline__ float wave_max(float v) {
  #pragma unroll
  for (int o = 32; o; o >>= 1) v = fmaxf(v, __shfl_xor(v, o));
  return v;
}

// Merged projection GEMM over 4608 rows (32-row x 64-col tiles, 576 blocks):
//   rows [0,512):    qp[row][h]   = queries * W_q   (row-major store)
//   rows [512,4608): kpT[b][h][k] = keys * W_k      (transposed store via LDS)
// 256 threads, 2x4 micro-tile, 1-tile register prefetch.
__global__ __launch_bounds__(256) void proj_merged_kernel(
    const float* __restrict__ queries, const float* __restrict__ keys,
    const float* __restrict__ W_q, const float* __restrict__ W_k,
    float* __restrict__ qp, float* __restrict__ kpT) {
  __shared__ float As[16 * 36];   // [k16][row32] (+pad)
  __shared__ float Ws[16 * 68];   // [k16][col64] (+pad)
  __shared__ float Ts[64 * 36];   // transpose staging [h64][k32] (+pad)
  const int tid  = threadIdx.x;
  const int row0 = blockIdx.x * 32;
  const int col0 = blockIdx.y * 64;
  const bool isQ = row0 < 512;
  const float* A = isQ ? queries + (size_t)row0 * DD_
                       : keys + (size_t)(row0 - 512) * DD_;
  const float* W = isQ ? W_q : W_k;
  const int ld_d = tid & 15, ld_r = tid >> 4;   // A loader: 16 d x 16 r (x2 passes)
  const int lw_n = tid & 63, lw_k = tid >> 6;   // W loader: 64 n x 4 k (x4 passes)
  const int tn = tid & 15, tm = tid >> 4;       // compute: 16 cols x 16 rows

  float aP[2], wP[4];
  #pragma unroll
  for (int p = 0; p < 2; ++p) aP[p] = A[(size_t)(p * 16 + ld_r) * DD_ + ld_d];
  #pragma unroll
  for (int p = 0; p < 4; ++p) wP[p] = W[(size_t)(p * 4 + lw_k) * H_ + col0 + lw_n];

  float acc[2][4] = {};
  for (int kt = 0; kt < 16; ++kt) {
    __syncthreads();   // previous compute done reading LDS
    #pragma unroll
    for (int p = 0; p < 2; ++p) As[ld_d * 36 + p * 16 + ld_r] = aP[p];
    #pragma unroll
    for (int p = 0; p < 4; ++p) Ws[(p * 4 + lw_k) * 68 + lw_n] = wP[p];
    __syncthreads();
    if (kt < 15) {     // prefetch next k-tile while computing this one
      const int k0 = (kt + 1) * 16;
      #pragma unroll
      for (int p = 0; p < 2; ++p) aP[p] = A[(size_t)(p * 16 + ld_r) * DD_ + k0 + ld_d];
      #pragma unroll
      for (int p = 0; p < 4; ++p) wP[p] = W[(size_t)(k0 + p * 4 + lw_k) * H_ + col0 + lw_n];
    }
    #pragma unroll
    for (int kk = 0; kk < 16; ++kk) {
      const float2 a = *(const float2*)&As[kk * 36 + tm * 2];
      const float4 w = *(const float4*)&Ws[kk * 68 + tn * 4];
      acc[0][0] = fmaf(a.x, w.x, acc[0][0]);
      acc[0][1] = fmaf(a.x, w.y, acc[0][1]);
      acc[0][2] = fmaf(a.x, w.z, acc[0][2]);
      acc[0][3] = fmaf(a.x, w.w, acc[0][3]);
      acc[1][0] = fmaf(a.y, w.x, acc[1][0]);
      acc[1][1] = fmaf(a.y, w.y, acc[1][1]);
      acc[1][2] = fmaf(a.y, w.z, acc[1][2]);
      acc[1][3] = fmaf(a.y, w.w, acc[1][3]);
    }
  }

  if (isQ) {
    #pragma unroll
    for (int i = 0; i < 2; ++i) {
      *(float4*)&qp[(size_t)(row0 + tm * 2 + i) * H_ + col0 + tn * 4] =
          make_float4(acc[i][0], acc[i][1], acc[i][2], acc[i][3]);
    }
  } else {
    // Transpose 32(k) x 64(h) tile in LDS, then coalesced float4 stores.
    #pragma unroll
    for (int i = 0; i < 2; ++i)
      #pragma unroll
      for (int j = 0; j < 4; ++j)
        Ts[(tn * 4 + j) * 36 + tm * 2 + i] = acc[i][j];
    __syncthreads();
    const int keyrow = row0 - 512;
    const int b = keyrow >> 10;            // NK_=1024 rows per batch
    const int kbase = keyrow & (NK_ - 1);
    const int hh = tid >> 2;               // 64 h rows
    const int kg = (tid & 3) * 8;          // 8-k group within the 32-k tile
    float* dst = kpT + ((size_t)(b * H_ + col0 + hh)) * NK_ + kbase + kg;
    #pragma unroll
    for (int p = 0; p < 2; ++p)
      *(float4*)&dst[p * 4] = *(const float4*)&Ts[hh * 36 + kg + p * 4];
  }
}

// Fused scores + masked softmax + PV.  One block per 2 q rows; 512 threads.
// Phase 1: group g = tid>>8 covers h in [128g,128g+128); thread owns k = 4t..4t+3
//   for BOTH q rows, with 4-deep register prefetch over h (hides L2 latency).
//   score = wsum - sum_h (2 v_h) * rcp(1 + exp2((q_h+k_h)*2*log2e))  [tanh identity]
//   Threads with k >= valid_len skip the h-loop entirely.
// Phase 2: combine h-halves, masked softmax per q row.
// Phase 3: wave w owns k in [128w,128w+128) ∩ [0,vl), 4-deep V prefetch.
__global__ __launch_bounds__(512) void fused_attn_kernel(
    const float* __restrict__ qp, const float* __restrict__ kpT,
    const float* __restrict__ v_w, const float* __restrict__ values,
    const int* __restrict__ valid_lens, float* __restrict__ out) {
  __shared__ float2 qs2[H_];            // {q0*C2, q1*C2}
  __shared__ float w2s[H_];
  __shared__ float reds[4];
  __shared__ float s_half[2][2][NK_];   // [h-half][qi][k] partial sums -> weights
  __shared__ float redm[2][4];
  __shared__ float redsum[2][4];
  __shared__ float red[8][2][DV_];

  const int tid = threadIdx.x;  // 0..511
  // Batch<->XCD affinity: XCD pair {2b,2b+1} only touches batch b.
  const int n = blockIdx.x;     // 0..255
  const int xcd = n & 7;
  const int b = xcd >> 1;
  const int idx = ((n >> 3) << 1) | (xcd & 1);  // 0..63 q-pair within batch
  const int qrow = b * NQ_ + idx * 2;

  int vl = valid_lens[b];
  vl = vl < 1 ? 1 : (vl > NK_ ? NK_ : vl);

  const float C2 = 2.8853900817779268f;  // 2*log2(e)
  if (tid < H_) {
    const float vw = v_w[tid];
    w2s[tid] = 2.0f * vw;
    const float q0 = qp[(size_t)qrow * H_ + tid];
    const float q1 = qp[(size_t)(qrow + 1) * H_ + tid];
    qs2[tid] = make_float2(q0 * C2, q1 * C2);
    float s = wave_sum(vw);
    if ((tid & 63) == 0) reds[tid >> 6] = s;
  }
  __syncthreads();
  const float wsum = reds[0] + reds[1] + reds[2] + reds[3];

  // ---- Phase 1: partial score sums over this group's h-half ----
  const int g = tid >> 8;
  const int k0 = (tid & 255) * 4;
  if (k0 < vl) {
    float a0x = 0.f, a0y = 0.f, a0z = 0.f, a0w = 0.f;
    float a1x = 0.f, a1y = 0.f, a1z = 0.f, a1w = 0.f;
    const float* kp = kpT + ((size_t)(b * H_ + g * 128)) * NK_ + k0;
    const float* w2p = w2s + g * 128;
    const float2* q2p = qs2 + g * 128;
    float4 c0 = *(const float4*)(kp + 0 * (size_t)NK_);
    float4 c1 = *(const float4*)(kp + 1 * (size_t)NK_);
    float4 c2 = *(const float4*)(kp + 2 * (size_t)NK_);
    float4 c3 = *(const float4*)(kp + 3 * (size_t)NK_);
#define CONSUME(kv, h)                                                     \
    {                                                                      \
      const float w2 = w2p[h];                                             \
      const float2 q2 = q2p[h];                                            \
      const float e0x = __builtin_amdgcn_exp2f(fmaf((kv).x, C2, q2.x));    \
      const float e0y = __builtin_amdgcn_exp2f(fmaf((kv).y, C2, q2.x));    \
      const float e0z = __builtin_amdgcn_exp2f(fmaf((kv).z, C2, q2.x));    \
      const float e0w = __builtin_amdgcn_exp2f(fmaf((kv).w, C2, q2.x));    \
      const float e1x = __builtin_amdgcn_exp2f(fmaf((kv).x, C2, q2.y));    \
      const float e1y = __builtin_amdgcn_exp2f(fmaf((kv).y, C2, q2.y));    \
      const float e1z = __builtin_amdgcn_exp2f(fmaf((kv).z, C2, q2.y));    \
      const float e1w = __builtin_amdgcn_exp2f(fmaf((kv).w, C2, q2.y));    \
      a0x = fmaf(w2, __builtin_amdgcn_rcpf(1.0f + e0x), a0x);              \
      a0y = fmaf(w2, __builtin_amdgcn_rcpf(1.0f + e0y), a0y);              \
      a0z = fmaf(w2, __builtin_amdgcn_rcpf(1.0f + e0z), a0z);              \
      a0w = fmaf(w2, __builtin_amdgcn_rcpf(1.0f + e0w), a0w);              \
      a1x = fmaf(w2, __builtin_amdgcn_rcpf(1.0f + e1x), a1x);              \
      a1y = fmaf(w2, __builtin_amdgcn_rcpf(1.0f + e1y), a1y);              \
      a1z = fmaf(w2, __builtin_amdgcn_rcpf(1.0f + e1z), a1z);              \
      a1w = fmaf(w2, __builtin_amdgcn_rcpf(1.0f + e1w), a1w);              \
    }
    for (int gg = 0; gg < 31; ++gg) {
      const int hb = gg * 4;
      const float4 n0 = *(const float4*)(kp + (size_t)(hb + 4) * NK_);
      const float4 n1 = *(const float4*)(kp + (size_t)(hb + 5) * NK_);
      const float4 n2 = *(const float4*)(kp + (size_t)(hb + 6) * NK_);
      const float4 n3 = *(const float4*)(kp + (size_t)(hb + 7) * NK_);
      CONSUME(c0, hb + 0)
      CONSUME(c1, hb + 1)
      CONSUME(c2, hb + 2)
      CONSUME(c3, hb + 3)
      c0 = n0; c1 = n1; c2 = n2; c3 = n3;
    }
    CONSUME(c0, 124)
    CONSUME(c1, 125)
    CONSUME(c2, 126)
    CONSUME(c3, 127)
#undef CONSUME
    *(float4*)&s_half[g][0][k0] = make_float4(a0x, a0y, a0z, a0w);
    *(float4*)&s_half[g][1][k0] = make_float4(a1x, a1y, a1z, a1w);
  }
  __syncthreads();

  // ---- Phase 2: combine halves + masked softmax per q row ----
  const int qi = tid >> 8;
  const int k4 = (tid & 255) * 4;
  const float4 pA = *(const float4*)&s_half[0][qi][k4];
  const float4 pB = *(const float4*)&s_half[1][qi][k4];
  const float s0 = wsum - (pA.x + pB.x);
  const float s1 = wsum - (pA.y + pB.y);
  const float s2 = wsum - (pA.z + pB.z);
  const float s3 = wsum - (pA.w + pB.w);
  const float NEG = -3.0e38f;
  float m = NEG;
  m = fmaxf(m, (k4 + 0 < vl) ? s0 : NEG);
  m = fmaxf(m, (k4 + 1 < vl) ? s1 : NEG);
  m = fmaxf(m, (k4 + 2 < vl) ? s2 : NEG);
  m = fmaxf(m, (k4 + 3 < vl) ? s3 : NEG);
  m = wave_max(m);
  if ((tid & 63) == 0) redm[qi][(tid >> 6) & 3] = m;
  __syncthreads();
  const float M = fmaxf(fmaxf(redm[qi][0], redm[qi][1]),
                        fmaxf(redm[qi][2], redm[qi][3]));
  const float CE = 1.4426950408889634f;  // log2(e)
  const float p0 = (k4 + 0 < vl) ? __builtin_amdgcn_exp2f((s0 - M) * CE) : 0.0f;
  const float p1 = (k4 + 1 < vl) ? __builtin_amdgcn_exp2f((s1 - M) * CE) : 0.0f;
  const float p2 = (k4 + 2 < vl) ? __builtin_amdgcn_exp2f((s2 - M) * CE) : 0.0f;
  const float p3 = (k4 + 3 < vl) ? __builtin_amdgcn_exp2f((s3 - M) * CE) : 0.0f;
  float psum = wave_sum(p0 + p1 + p2 + p3);
  if ((tid & 63) == 0) redsum[qi][(tid >> 6) & 3] = psum;
  __syncthreads();
  const float S = redsum[qi][0] + redsum[qi][1] + redsum[qi][2] + redsum[qi][3];
  const float inv = 1.0f / S;
  *(float4*)&s_half[0][qi][k4] = make_float4(p0 * inv, p1 * inv, p2 * inv, p3 * inv);
  __syncthreads();

  // ---- Phase 3: PV with 4-deep V prefetch ----
  const int w = tid >> 6;
  const int lane = tid & 63;
  const int d0 = lane * 4;
  float4 pa0 = make_float4(0.f, 0.f, 0.f, 0.f);
  float4 pa1 = make_float4(0.f, 0.f, 0.f, 0.f);
  const int kbeg = w * (NK_ / 8);
  const int kend = (kbeg + NK_ / 8) < vl ? (kbeg + NK_ / 8) : vl;
  const float* vb = values + (size_t)b * NK_ * DV_ + d0;
#define PVSTEP(v4, kk)                                                     \
    {                                                                      \
      const float w0 = s_half[0][0][kk];                                   \
      const float w1 = s_half[0][1][kk];                                   \
      pa0.x = fmaf(w0, (v4).x, pa0.x);                                     \
      pa0.y = fmaf(w0, (v4).y, pa0.y);                                     \
      pa0.z = fmaf(w0, (v4).z, pa0.z);                                     \
      pa0.w = fmaf(w0, (v4).w, pa0.w);                                     \
      pa1.x = fmaf(w1, (v4).x, pa1.x);                                     \
      pa1.y = fmaf(w1, (v4).y, pa1.y);                                     \
      pa1.z = fmaf(w1, (v4).z, pa1.z);                                     \
      pa1.w = fmaf(w1, (v4).w, pa1.w);                                     \
    }
  int k = kbeg;
  if (k + 4 <= kend) {
    float4 v0 = *(const float4*)(vb + (size_t)(k + 0) * DV_);
    float4 v1 = *(const float4*)(vb + (size_t)(k + 1) * DV_);
    float4 v2 = *(const float4*)(vb + (size_t)(k + 2) * DV_);
    float4 v3 = *(const float4*)(vb + (size_t)(k + 3) * DV_);
    for (; k + 8 <= kend; k += 4) {
      const float4 u0 = *(const float4*)(vb + (size_t)(k + 4) * DV_);
      const float4 u1 = *(const float4*)(vb + (size_t)(k + 5) * DV_);
      const float4 u2 = *(const float4*)(vb + (size_t)(k + 6) * DV_);
      const float4 u3 = *(const float4*)(vb + (size_t)(k + 7) * DV_);
      PVSTEP(v0, k + 0)
      PVSTEP(v1, k + 1)
      PVSTEP(v2, k + 2)
      PVSTEP(v3, k + 3)
      v0 = u0; v1 = u1; v2 = u2; v3 = u3;
    }
    PVSTEP(v0, k + 0)
    PVSTEP(v1, k + 1)
    PVSTEP(v2, k + 2)
    PVSTEP(v3, k + 3)
    k += 4;
  }
  for (; k < kend; ++k) {
    const float4 v4 = *(const float4*)(vb + (size_t)k * DV_);
    PVSTEP(v4, k)
  }
#undef PVSTEP
  *(float4*)&red[w][0][d0] = pa0;
  *(float4*)&red[w][1][d0] = pa1;
  __syncthreads();

  // Combine 8 wave-partials; coalesced store.
  const int oqi = tid >> 8;
  const int d = tid & 255;
  float s = 0.f;
  #pragma unroll
  for (int ww = 0; ww < 8; ++ww) s += red[ww][oqi][d];
  out[(size_t)(qrow + oqi) * DV_ + d] = s;
}

extern "C" void kernel_launch(void* const* d_in, const int* in_sizes, int n_in,
                              void* d_out, int out_size, void* d_ws, size_t ws_size,
                              hipStream_t stream) {
  const float* queries = (const float*)d_in[0];  // (B, NQ, DQ)
  const float* keys    = (const float*)d_in[1];  // (B, NK, DK)
  const float* values  = (const float*)d_in[2];  // (B, NK, DV)
  const int*   vlens   = (const int*)d_in[3];    // (B,)
  const float* W_q     = (const float*)d_in[4];  // (DQ, H)
  const float* W_k     = (const float*)d_in[5];  // (DK, H)
  const float* v_w     = (const float*)d_in[6];  // (H,)
  float* out = (float*)d_out;                    // (B, NQ, DV)

  // Workspace layout (floats): qp | kpT  = 0.5MB + 4MB
  float* qp  = (float*)d_ws;                  // [B*NQ][H]
  float* kpT = qp + (size_t)B_ * NQ_ * H_;    // [B][H][NK]

  proj_merged_kernel<<<dim3((512 + B_ * NK_) / 32, H_ / 64), 256, 0, stream>>>(
      queries, keys, W_q, W_k, qp, kpT);
  fused_attn_kernel<<<(B_ * NQ_) / 2, 512, 0, stream>>>(qp, kpT, v_w, values, vlens, out);
}